// Round 1
// baseline (1421.518 us; speedup 1.0000x reference)
//
#include <hip/hip_runtime.h>
#include <hip/hip_bf16.h>

#define EPSF  1e-7f
#define MINNF 1e-15f

__device__ __forceinline__ float wredsum(float v){
  #pragma unroll
  for (int m = 32; m; m >>= 1) v += __shfl_xor(v, m, 64);
  return v;
}

__device__ __forceinline__ float arcoshf_(float x){
  float xc = fmaxf(x, 1.0f);
  return __logf(fmaxf(xc + sqrtf(fmaxf(xc*xc - 1.0f, 0.0f)), MINNF));
}

__device__ __forceinline__ void sinhcosh_(float x, float& sh, float& ch){
  float xc = fminf(fmaxf(x, -15.0f), 15.0f);
  float e  = __expf(xc);
  float ei = 1.0f / e;
  ch = 0.5f * (e + ei);
  sh = 0.5f * (e - ei);
}

// ---------------- per-node: L = logmap0(x) ----------------
__global__ __launch_bounds__(256) void k_logmap0(const float* __restrict__ X,
                                                 float* __restrict__ L, int N){
  int wid  = (blockIdx.x * blockDim.x + threadIdx.x) >> 6;
  int lane = threadIdx.x & 63;
  if (wid >= N) return;
  const float2 xv = *(const float2*)&X[(size_t)wid*128 + lane*2];
  float x0 = __shfl(xv.x, 0, 64);
  float ax = (lane == 0) ? 0.0f : xv.x;
  float yn2 = wredsum(ax*ax + xv.y*xv.y);
  float yn  = fmaxf(sqrtf(yn2), MINNF);
  float theta = fmaxf(x0, 1.0f + EPSF);
  float s = arcoshf_(theta) / yn;
  float2 o;
  o.x = (lane == 0) ? 0.0f : s * xv.x;
  o.y = s * xv.y;
  *(float2*)&L[(size_t)wid*128 + lane*2] = o;
}

// ---------------- per-node: out = expmap0(Z) ----------------
__global__ __launch_bounds__(256) void k_expmap0(const float* __restrict__ Z,
                                                 float* __restrict__ O, int N){
  int wid  = (blockIdx.x * blockDim.x + threadIdx.x) >> 6;
  int lane = threadIdx.x & 63;
  if (wid >= N) return;
  const float2 zv = *(const float2*)&Z[(size_t)wid*128 + lane*2];
  float zx = (lane == 0) ? 0.0f : zv.x;
  float xn2 = wredsum(zx*zx + zv.y*zv.y);
  float xn  = fmaxf(sqrtf(xn2), MINNF);
  float sh, ch; sinhcosh_(xn, sh, ch);
  float s = sh / xn;
  float ox = s * zx;           // lane0 -> 0
  float oy = s * zv.y;
  float s2 = wredsum(ox*ox + oy*oy);
  float o0 = sqrtf(fmaxf(1.0f + s2, EPSF));
  if (lane == 0) ox = o0;
  float2 o; o.x = ox; o.y = oy;
  *(float2*)&O[(size_t)wid*128 + lane*2] = o;
}

// ---------------- per-edge: msg = logmap(out[src], x[dst]); atomic aggr ----------------
__global__ __launch_bounds__(256) void k_edge(const float* __restrict__ OUT,
                                              const float* __restrict__ X,
                                              const int* __restrict__ src,
                                              const int* __restrict__ dst,
                                              float* __restrict__ AGG, int E){
  int e    = (blockIdx.x * blockDim.x + threadIdx.x) >> 6;
  int lane = threadIdx.x & 63;
  if (e >= E) return;
  int s = src[e], d = dst[e];
  const float2 a = *(const float2*)&OUT[(size_t)s*128 + lane*2];
  const float2 b = *(const float2*)&X  [(size_t)d*128 + lane*2];
  float a0 = __shfl(a.x, 0, 64);
  float b0 = __shfl(b.x, 0, 64);
  float dotab = wredsum(a.x*b.x + a.y*b.y);
  float md_ab = dotab - 2.0f*a0*b0;
  float xy = fminf(md_ab + 1.0f, -EPSF) - 1.0f;
  float2 u; u.x = b.x + xy*a.x; u.y = b.y + xy*a.y;
  float u0 = b0 + xy*a0;
  float dotuu = wredsum(u.x*u.x + u.y*u.y);
  float md_uu = dotuu - 2.0f*u0*u0;
  float nu = fmaxf(sqrtf(fmaxf(md_uu, EPSF)), MINNF);
  float th = fmaxf(-md_ab, 1.0f + EPSF);
  float arc = arcoshf_(th);
  float dist = sqrtf(fminf(arc*arc, 50.0f));
  float sc = dist / nu;
  float vx = sc * u.x, vy = sc * u.y;
  float v0 = sc * u0;
  float dotav = wredsum(a.x*vx + a.y*vy);
  float v0p = (dotav - a0*v0) / fmaxf(a0, EPSF);
  if (lane == 0) vx = v0p;
  atomicAdd(&AGG[(size_t)d*128 + lane*2    ], vx);
  atomicAdd(&AGG[(size_t)d*128 + lane*2 + 1], vy);
}

// ---------------- per-node finish: expmap + relu(poincare) + to_hyperboloid ----------------
__global__ __launch_bounds__(256) void k_node(const float* __restrict__ AGG,
                                              const float* __restrict__ X,
                                              float* __restrict__ XN, int N){
  int wid  = (blockIdx.x * blockDim.x + threadIdx.x) >> 6;
  int lane = threadIdx.x & 63;
  if (wid >= N) return;
  const float2 u  = *(const float2*)&AGG[(size_t)wid*128 + lane*2];
  const float2 xv = *(const float2*)&X  [(size_t)wid*128 + lane*2];
  float u0 = __shfl(u.x, 0, 64);
  float dotuu = wredsum(u.x*u.x + u.y*u.y);
  float md = dotuu - 2.0f*u0*u0;
  float theta = fmaxf(fminf(sqrtf(fmaxf(md, EPSF)), 1e6f), MINNF);
  float sh, ch; sinhcosh_(theta, sh, ch);
  float s = sh / theta;
  float hx = ch*xv.x + s*u.x;
  float hy = ch*xv.y + s*u.y;
  float hxm = (lane == 0) ? 0.0f : hx;          // proj drops elem0
  float hh = wredsum(hxm*hxm + hy*hy);
  float h0 = sqrtf(fmaxf(1.0f + hh, EPSF));
  float inv = 1.0f / (h0 + 1.0f);
  float px = fmaxf(hxm*inv, 0.0f);
  float py = fmaxf(hy *inv, 0.0f);
  float sq = wredsum(px*px + py*py);
  float idn = 1.0f / (1.0f - sq);
  float2 o;
  o.x = (lane == 0) ? (1.0f + sq)*idn : 2.0f*px*idn;
  o.y = 2.0f*py*idn;
  *(float2*)&XN[(size_t)wid*128 + lane*2] = o;
}

// ---------------- tiled f32 GEMM: C[n][j] = sum_c sum_k Ac[n][k]*W[j][c*128+k] (+bias) ----------------
__global__ __launch_bounds__(256) void gemm_k(const float* __restrict__ A0,
                                              const float* __restrict__ A1,
                                              const float* __restrict__ A2,
                                              const float* __restrict__ W,
                                              const float* __restrict__ bias,
                                              float* __restrict__ C, int N, int nchunk){
  __shared__ float Wsm[128*132];
  __shared__ float Asm[32*128];
  int tid  = threadIdx.x;
  int base = blockIdx.x * 32;
  int j    = tid & 127;
  int half = tid >> 7;
  int ldw  = nchunk * 128;
  float acc[16];
  #pragma unroll
  for (int i = 0; i < 16; i++) acc[i] = 0.0f;

  for (int c = 0; c < nchunk; c++){
    const float* Ac = (c == 0) ? A0 : ((c == 1) ? A1 : A2);
    for (int t = tid; t < 4096; t += 256){            // 128x128 W chunk as float4
      int jr = t >> 5, k4 = t & 31;
      float4 v = *(const float4*)&W[(size_t)jr*ldw + c*128 + k4*4];
      *(float4*)&Wsm[jr*132 + k4*4] = v;
    }
    for (int t = tid; t < 1024; t += 256){            // 32x128 A tile as float4
      int nl = t >> 5, k4 = t & 31;
      int node = base + nl;
      float4 v = make_float4(0.f,0.f,0.f,0.f);
      if (node < N) v = *(const float4*)&Ac[(size_t)node*128 + k4*4];
      *(float4*)&Asm[nl*128 + k4*4] = v;
    }
    __syncthreads();
    #pragma unroll 4
    for (int k4 = 0; k4 < 32; k4++){
      float4 w = *(const float4*)&Wsm[j*132 + k4*4];
      #pragma unroll
      for (int i = 0; i < 16; i++){
        float4 a = *(const float4*)&Asm[(half*16 + i)*128 + k4*4];
        acc[i] += a.x*w.x + a.y*w.y + a.z*w.z + a.w*w.w;
      }
    }
    __syncthreads();
  }
  float bv = bias ? bias[j] : 0.0f;
  #pragma unroll
  for (int i = 0; i < 16; i++){
    int node = base + half*16 + i;
    if (node < N) C[(size_t)node*128 + j] = acc[i] + bv;
  }
}

extern "C" void kernel_launch(void* const* d_in, const int* in_sizes, int n_in,
                              void* d_out, int out_size, void* d_ws, size_t ws_size,
                              hipStream_t stream) {
  const float* x0 = (const float*)d_in[0];
  const int*   ei = (const int*)  d_in[1];
  const float* W0 = (const float*)d_in[2];
  const float* W1 = (const float*)d_in[3];
  const float* Wf = (const float*)d_in[4];
  const float* bf = (const float*)d_in[5];
  float* out = (float*)d_out;

  int N = in_sizes[0] / 128;
  int E = in_sizes[1] / 2;
  const int* src = ei;
  const int* dst = ei + E;

  size_t row = (size_t)N * 128;
  float* ws  = (float*)d_ws;
  float* x1  = ws;
  float* x2  = ws + row;
  float* tmp = ws + 2*row;
  float* agg = ws + 3*row;

  dim3 blk(256);
  int nodeBlocks = (N + 3) / 4;
  int edgeBlocks = (E + 3) / 4;
  int gemmBlocks = (N + 31) / 32;

  const float* xin = x0;
  float* xout = x1;
  const float* W = W0;
  for (int l = 0; l < 2; l++){
    k_logmap0<<<nodeBlocks, blk, 0, stream>>>(xin, tmp, N);
    gemm_k  <<<gemmBlocks, blk, 0, stream>>>(tmp, nullptr, nullptr, W, nullptr, agg, N, 1);
    k_expmap0<<<nodeBlocks, blk, 0, stream>>>(agg, tmp, N);
    hipMemsetAsync(agg, 0, row * sizeof(float), stream);
    k_edge  <<<edgeBlocks, blk, 0, stream>>>(tmp, xin, src, dst, agg, E);
    k_node  <<<nodeBlocks, blk, 0, stream>>>(agg, xin, xout, N);
    xin = xout; xout = x2; W = W1;
  }
  gemm_k<<<gemmBlocks, blk, 0, stream>>>(x0, x1, x2, Wf, bf, out, N, 3);
}

// Round 2
// 871.479 us; speedup vs baseline: 1.6312x; 1.6312x over previous
//
#include <hip/hip_runtime.h>
#include <hip/hip_bf16.h>

#define EPSF  1e-7f
#define MINNF 1e-15f

__device__ __forceinline__ float wredsum(float v){
  #pragma unroll
  for (int m = 32; m; m >>= 1) v += __shfl_xor(v, m, 64);
  return v;
}

__device__ __forceinline__ float arcoshf_(float x){
  float xc = fmaxf(x, 1.0f);
  return __logf(fmaxf(xc + sqrtf(fmaxf(xc*xc - 1.0f, 0.0f)), MINNF));
}

__device__ __forceinline__ void sinhcosh_(float x, float& sh, float& ch){
  float xc = fminf(fmaxf(x, -15.0f), 15.0f);
  float e  = __expf(xc);
  float ei = 1.0f / e;
  ch = 0.5f * (e + ei);
  sh = 0.5f * (e - ei);
}

// ---------------- CSR build ----------------
__global__ __launch_bounds__(256) void k_hist(const int* __restrict__ dst,
                                              int* __restrict__ deg, int E){
  int i = blockIdx.x * blockDim.x + threadIdx.x;
  if (i < E) atomicAdd(&deg[dst[i]], 1);
}

__global__ __launch_bounds__(1024) void k_scan(const int* __restrict__ deg,
                                               int* __restrict__ rowptr, int N){
  __shared__ int sm[1024];
  __shared__ int carrys;
  int tid = threadIdx.x;
  if (tid == 0){ carrys = 0; rowptr[0] = 0; }
  __syncthreads();
  for (int base = 0; base < N; base += 1024){
    int i = base + tid;
    int v = (i < N) ? deg[i] : 0;
    sm[tid] = v;
    __syncthreads();
    for (int off = 1; off < 1024; off <<= 1){
      int t = (tid >= off) ? sm[tid - off] : 0;
      __syncthreads();
      sm[tid] += t;
      __syncthreads();
    }
    int incl = sm[tid] + carrys;
    if (i < N) rowptr[i + 1] = incl;
    __syncthreads();
    if (tid == 1023) carrys = incl;
    __syncthreads();
  }
}

__global__ __launch_bounds__(256) void k_scatter(const int* __restrict__ src,
                                                 const int* __restrict__ dst,
                                                 int* __restrict__ cursor,
                                                 int* __restrict__ ssrc, int E){
  int i = blockIdx.x * blockDim.x + threadIdx.x;
  if (i < E){
    int pos = atomicAdd(&cursor[dst[i]], 1);
    ssrc[pos] = src[i];
  }
}

// ---------------- per-node: s_n = arcosh(theta)/||y||  (logmap0 row scale) ----------------
__global__ __launch_bounds__(256) void k_lognorm(const float* __restrict__ X,
                                                 float* __restrict__ S, int N){
  int wid  = (blockIdx.x * blockDim.x + threadIdx.x) >> 6;
  int lane = threadIdx.x & 63;
  if (wid >= N) return;
  const float2 xv = *(const float2*)&X[(size_t)wid*128 + lane*2];
  float x0 = __shfl(xv.x, 0, 64);
  float ax = (lane == 0) ? 0.0f : xv.x;
  float yn2 = wredsum(ax*ax + xv.y*xv.y);
  float yn  = fmaxf(sqrtf(yn2), MINNF);
  float theta = fmaxf(x0, 1.0f + EPSF);
  if (lane == 0) S[wid] = arcoshf_(theta) / yn;
}

// ---------------- per-node: out = expmap0(Z) (in-place safe) ----------------
__global__ __launch_bounds__(256) void k_expmap0(const float* __restrict__ Z,
                                                 float* __restrict__ O, int N){
  int wid  = (blockIdx.x * blockDim.x + threadIdx.x) >> 6;
  int lane = threadIdx.x & 63;
  if (wid >= N) return;
  const float2 zv = *(const float2*)&Z[(size_t)wid*128 + lane*2];
  float zx = (lane == 0) ? 0.0f : zv.x;
  float xn2 = wredsum(zx*zx + zv.y*zv.y);
  float xn  = fmaxf(sqrtf(xn2), MINNF);
  float sh, ch; sinhcosh_(xn, sh, ch);
  float s = sh / xn;
  float ox = s * zx;
  float oy = s * zv.y;
  float s2 = wredsum(ox*ox + oy*oy);
  float o0 = sqrtf(fmaxf(1.0f + s2, EPSF));
  if (lane == 0) ox = o0;
  float2 o; o.x = ox; o.y = oy;
  *(float2*)&O[(size_t)wid*128 + lane*2] = o;
}

// ---------------- fused: per dst-node register aggregation + expmap/relu/hyperboloid ----------------
// Uses <p,p>_M = -1 identities: m(u,u) = -1 + xy*(2m - xy),  m(a,v) = sc*(m - xy).
__global__ __launch_bounds__(256) void k_conv(const float* __restrict__ OUT,
                                              const float* __restrict__ X,
                                              const int* __restrict__ rowptr,
                                              const int* __restrict__ ssrc,
                                              float* __restrict__ XN, int N){
  int wid  = (blockIdx.x * blockDim.x + threadIdx.x) >> 6;
  int lane = threadIdx.x & 63;
  if (wid >= N) return;
  const float2 xv = *(const float2*)&X[(size_t)wid*128 + lane*2];
  float b0 = __shfl(xv.x, 0, 64);
  int beg = rowptr[wid], end = rowptr[wid + 1];
  float accx = 0.0f, accy = 0.0f;

  float2 a = make_float2(0.f, 0.f);
  if (beg < end){
    int s0i = ssrc[beg];
    a = *(const float2*)&OUT[(size_t)s0i*128 + lane*2];
  }
  for (int idx = beg; idx < end; ++idx){
    float2 ac = a;
    if (idx + 1 < end){
      int s2 = ssrc[idx + 1];
      a = *(const float2*)&OUT[(size_t)s2*128 + lane*2];   // prefetch next row
    }
    float a0 = __shfl(ac.x, 0, 64);
    float m  = wredsum(ac.x*xv.x + ac.y*xv.y) - 2.0f*a0*b0;   // Minkowski <a,b>
    float xy = fminf(m + 1.0f, -EPSF) - 1.0f;
    float ux = xv.x + xy*ac.x;
    float uy = xv.y + xy*ac.y;
    float u0 = b0   + xy*a0;
    float m_uu = -1.0f + xy*(2.0f*m - xy);
    float nu = fmaxf(sqrtf(fmaxf(m_uu, EPSF)), MINNF);
    float th = fmaxf(-m, 1.0f + EPSF);
    float arc = arcoshf_(th);
    float dist = fminf(arc, 7.07106781f);                     // sqrt(min(arc^2,50))
    float sc = __fdividef(dist, nu);
    float vx = sc*ux, vy = sc*uy;
    float v0 = sc*u0;
    float v0p = __fdividef(sc*(m - xy) + a0*v0, fmaxf(a0, EPSF));
    accx += (lane == 0) ? v0p : vx;
    accy += vy;
  }

  // expmap(aggr, x) + relu(poincare) + to_hyperboloid
  float u0 = __shfl(accx, 0, 64);
  float md = wredsum(accx*accx + accy*accy) - 2.0f*u0*u0;
  float theta = fmaxf(fminf(sqrtf(fmaxf(md, EPSF)), 1e6f), MINNF);
  float sh, ch; sinhcosh_(theta, sh, ch);
  float s = sh / theta;
  float hx = ch*xv.x + s*accx;
  float hy = ch*xv.y + s*accy;
  float hxm = (lane == 0) ? 0.0f : hx;
  float hh = wredsum(hxm*hxm + hy*hy);
  float h0 = sqrtf(fmaxf(1.0f + hh, EPSF));
  float inv = 1.0f / (h0 + 1.0f);
  float px = fmaxf(hxm*inv, 0.0f);
  float py = fmaxf(hy *inv, 0.0f);
  float sq = wredsum(px*px + py*py);
  float idn = 1.0f / (1.0f - sq);
  float2 o;
  o.x = (lane == 0) ? (1.0f + sq)*idn : 2.0f*px*idn;
  o.y = 2.0f*py*idn;
  *(float2*)&XN[(size_t)wid*128 + lane*2] = o;
}

// ---------------- tiled f32 GEMM: C[n][j] = sum_c sum_k Ac[n][k]*W[j][c*128+k] (+bias)
// If S != nullptr: A is logmap0(x) built on the fly = S[n] * (x row with elem0 zeroed).
__global__ __launch_bounds__(256) void gemm_k(const float* __restrict__ A0,
                                              const float* __restrict__ A1,
                                              const float* __restrict__ A2,
                                              const float* __restrict__ W,
                                              const float* __restrict__ bias,
                                              const float* __restrict__ S,
                                              float* __restrict__ C, int N, int nchunk){
  __shared__ float Wsm[128*132];
  __shared__ float Asm[32*128];
  int tid  = threadIdx.x;
  int base = blockIdx.x * 32;
  int j    = tid & 127;
  int half = tid >> 7;
  int ldw  = nchunk * 128;
  float acc[16];
  #pragma unroll
  for (int i = 0; i < 16; i++) acc[i] = 0.0f;

  for (int c = 0; c < nchunk; c++){
    const float* Ac = (c == 0) ? A0 : ((c == 1) ? A1 : A2);
    for (int t = tid; t < 4096; t += 256){            // 128x128 W chunk as float4
      int jr = t >> 5, k4 = t & 31;
      float4 v = *(const float4*)&W[(size_t)jr*ldw + c*128 + k4*4];
      *(float4*)&Wsm[jr*132 + k4*4] = v;
    }
    for (int t = tid; t < 1024; t += 256){            // 32x128 A tile as float4
      int nl = t >> 5, k4 = t & 31;
      int node = base + nl;
      float4 v = make_float4(0.f,0.f,0.f,0.f);
      if (node < N){
        v = *(const float4*)&Ac[(size_t)node*128 + k4*4];
        if (S){
          float sn = S[node];
          if (k4 == 0) v.x = 0.0f;                    // logmap0 zeroes elem 0
          v.x *= sn; v.y *= sn; v.z *= sn; v.w *= sn;
        }
      }
      *(float4*)&Asm[nl*128 + k4*4] = v;
    }
    __syncthreads();
    #pragma unroll 4
    for (int k4 = 0; k4 < 32; k4++){
      float4 w = *(const float4*)&Wsm[j*132 + k4*4];
      #pragma unroll
      for (int i = 0; i < 16; i++){
        float4 a = *(const float4*)&Asm[(half*16 + i)*128 + k4*4];
        acc[i] += a.x*w.x + a.y*w.y + a.z*w.z + a.w*w.w;
      }
    }
    __syncthreads();
  }
  float bv = bias ? bias[j] : 0.0f;
  #pragma unroll
  for (int i = 0; i < 16; i++){
    int node = base + half*16 + i;
    if (node < N) C[(size_t)node*128 + j] = acc[i] + bv;
  }
}

extern "C" void kernel_launch(void* const* d_in, const int* in_sizes, int n_in,
                              void* d_out, int out_size, void* d_ws, size_t ws_size,
                              hipStream_t stream) {
  const float* x0 = (const float*)d_in[0];
  const int*   ei = (const int*)  d_in[1];
  const float* W0 = (const float*)d_in[2];
  const float* W1 = (const float*)d_in[3];
  const float* Wf = (const float*)d_in[4];
  const float* bf = (const float*)d_in[5];
  float* out = (float*)d_out;

  int N = in_sizes[0] / 128;
  int E = in_sizes[1] / 2;
  const int* src = ei;
  const int* dst = ei + E;

  size_t row = (size_t)N * 128;
  float* ws = (float*)d_ws;
  float* x1 = ws;                 // conv1 output
  float* x2 = ws + row;           // conv2 output
  float* g  = ws + 2*row;         // gemm out -> expmap0 in-place
  float* Sv = ws + 3*row;         // N floats (logmap0 scale)
  int* rowptr = (int*)(Sv + N);   // N+1
  int* cursor = rowptr + (N + 1); // N (also used as deg)
  int* ssrc   = cursor + N;       // E

  dim3 blk(256);
  int nodeBlocks = (N + 3) / 4;
  int eThreads   = (E + 255) / 256;
  int gemmBlocks = (N + 31) / 32;

  // ---- CSR build (once; shared by both layers) ----
  hipMemsetAsync(cursor, 0, (size_t)N * sizeof(int), stream);          // deg = 0
  k_hist<<<eThreads, blk, 0, stream>>>(dst, cursor, E);
  k_scan<<<1, 1024, 0, stream>>>(cursor, rowptr, N);
  hipMemcpyAsync(cursor, rowptr, (size_t)N * sizeof(int),
                 hipMemcpyDeviceToDevice, stream);
  k_scatter<<<eThreads, blk, 0, stream>>>(src, dst, cursor, ssrc, E);

  const float* xin = x0;
  float* xout = x1;
  const float* W = W0;
  for (int l = 0; l < 2; l++){
    k_lognorm<<<nodeBlocks, blk, 0, stream>>>(xin, Sv, N);
    gemm_k  <<<gemmBlocks, blk, 0, stream>>>(xin, nullptr, nullptr, W, nullptr, Sv, g, N, 1);
    k_expmap0<<<nodeBlocks, blk, 0, stream>>>(g, g, N);
    k_conv  <<<nodeBlocks, blk, 0, stream>>>(g, xin, rowptr, ssrc, xout, N);
    xin = xout; xout = x2; W = W1;
  }
  gemm_k<<<gemmBlocks, blk, 0, stream>>>(x0, x1, x2, Wf, bf, nullptr, out, N, 3);
}

// Round 3
// 654.976 us; speedup vs baseline: 2.1703x; 1.3306x over previous
//
#include <hip/hip_runtime.h>
#include <hip/hip_bf16.h>

#define EPSF  1e-7f
#define MINNF 1e-15f

__device__ __forceinline__ float wredsum(float v){
  #pragma unroll
  for (int m = 32; m; m >>= 1) v += __shfl_xor(v, m, 64);
  return v;
}

__device__ __forceinline__ float arcoshf_(float x){
  float xc = fmaxf(x, 1.0f);
  return __logf(fmaxf(xc + sqrtf(fmaxf(xc*xc - 1.0f, 0.0f)), MINNF));
}

__device__ __forceinline__ void sinhcosh_(float x, float& sh, float& ch){
  float xc = fminf(fmaxf(x, -15.0f), 15.0f);
  float e  = __expf(xc);
  float ei = 1.0f / e;
  ch = 0.5f * (e + ei);
  sh = 0.5f * (e - ei);
}

// ---------------- CSR build ----------------
__global__ __launch_bounds__(256) void k_hist(const int* __restrict__ dst,
                                              int* __restrict__ deg, int E){
  int i = blockIdx.x * blockDim.x + threadIdx.x;
  if (i < E) atomicAdd(&deg[dst[i]], 1);
}

__global__ __launch_bounds__(1024) void k_scan(const int* __restrict__ deg,
                                               int* __restrict__ rowptr, int N){
  __shared__ int wsum[16];
  __shared__ int carry;
  int tid = threadIdx.x, lane = tid & 63, wv = tid >> 6;
  if (tid == 0){ carry = 0; rowptr[0] = 0; }
  __syncthreads();
  for (int bse = 0; bse < N; bse += 1024){
    int i = bse + tid;
    int v = (i < N) ? deg[i] : 0;
    int s = v;
    #pragma unroll
    for (int off = 1; off < 64; off <<= 1){
      int t = __shfl_up(s, off, 64);
      if (lane >= off) s += t;
    }
    if (lane == 63) wsum[wv] = s;
    __syncthreads();
    if (wv == 0){
      int ws = (lane < 16) ? wsum[lane] : 0;
      #pragma unroll
      for (int off = 1; off < 16; off <<= 1){
        int t = __shfl_up(ws, off, 64);
        if (lane >= off) ws += t;
      }
      if (lane < 16) wsum[lane] = ws;
    }
    __syncthreads();
    int incl = s + (wv ? wsum[wv - 1] : 0) + carry;
    if (i < N) rowptr[i + 1] = incl;
    __syncthreads();
    if (tid == 1023) carry = incl;
    __syncthreads();
  }
}

__global__ __launch_bounds__(256) void k_scatter(const int* __restrict__ src,
                                                 const int* __restrict__ dst,
                                                 int* __restrict__ cursor,
                                                 int* __restrict__ ssrc, int E){
  int i = blockIdx.x * blockDim.x + threadIdx.x;
  if (i < E){
    int pos = atomicAdd(&cursor[dst[i]], 1);
    ssrc[pos] = src[i];
  }
}

// ---------------- per-node: s_n = arcosh(theta)/||y||  (logmap0 row scale) ----------------
__global__ __launch_bounds__(256) void k_lognorm(const float* __restrict__ X,
                                                 float* __restrict__ S, int N){
  int wid  = (blockIdx.x * blockDim.x + threadIdx.x) >> 6;
  int lane = threadIdx.x & 63;
  if (wid >= N) return;
  const float2 xv = *(const float2*)&X[(size_t)wid*128 + lane*2];
  float x0 = __shfl(xv.x, 0, 64);
  float ax = (lane == 0) ? 0.0f : xv.x;
  float yn2 = wredsum(ax*ax + xv.y*xv.y);
  float yn  = fmaxf(sqrtf(yn2), MINNF);
  float theta = fmaxf(x0, 1.0f + EPSF);
  if (lane == 0) S[wid] = arcoshf_(theta) / yn;
}

// ---------------- per-node: out = expmap0(Z) (in-place safe) ----------------
__global__ __launch_bounds__(256) void k_expmap0(const float* __restrict__ Z,
                                                 float* __restrict__ O, int N){
  int wid  = (blockIdx.x * blockDim.x + threadIdx.x) >> 6;
  int lane = threadIdx.x & 63;
  if (wid >= N) return;
  const float2 zv = *(const float2*)&Z[(size_t)wid*128 + lane*2];
  float zx = (lane == 0) ? 0.0f : zv.x;
  float xn2 = wredsum(zx*zx + zv.y*zv.y);
  float xn  = fmaxf(sqrtf(xn2), MINNF);
  float sh, ch; sinhcosh_(xn, sh, ch);
  float s = sh / xn;
  float ox = s * zx;
  float oy = s * zv.y;
  float s2 = wredsum(ox*ox + oy*oy);
  float o0 = sqrtf(fmaxf(1.0f + s2, EPSF));
  if (lane == 0) ox = o0;
  float2 o; o.x = ox; o.y = oy;
  *(float2*)&O[(size_t)wid*128 + lane*2] = o;
}

// ---------------- fused: per dst-node register aggregation + expmap/relu/hyperboloid ----------------
__global__ __launch_bounds__(256) void k_conv(const float* __restrict__ OUT,
                                              const float* __restrict__ X,
                                              const int* __restrict__ rowptr,
                                              const int* __restrict__ ssrc,
                                              float* __restrict__ XN, int N){
  int wid  = (blockIdx.x * blockDim.x + threadIdx.x) >> 6;
  int lane = threadIdx.x & 63;
  if (wid >= N) return;
  const float2 xv = *(const float2*)&X[(size_t)wid*128 + lane*2];
  float b0 = __shfl(xv.x, 0, 64);
  int beg = rowptr[wid], end = rowptr[wid + 1];
  float accx = 0.0f, accy = 0.0f;

  float2 a = make_float2(0.f, 0.f);
  if (beg < end){
    int s0i = ssrc[beg];
    a = *(const float2*)&OUT[(size_t)s0i*128 + lane*2];
  }
  for (int idx = beg; idx < end; ++idx){
    float2 ac = a;
    if (idx + 1 < end){
      int s2 = ssrc[idx + 1];
      a = *(const float2*)&OUT[(size_t)s2*128 + lane*2];   // prefetch next row
    }
    float a0 = __shfl(ac.x, 0, 64);
    float m  = wredsum(ac.x*xv.x + ac.y*xv.y) - 2.0f*a0*b0;   // Minkowski <a,b>
    float xy = fminf(m + 1.0f, -EPSF) - 1.0f;
    float ux = xv.x + xy*ac.x;
    float uy = xv.y + xy*ac.y;
    float u0 = b0   + xy*a0;
    float m_uu = -1.0f + xy*(2.0f*m - xy);
    float nu = fmaxf(sqrtf(fmaxf(m_uu, EPSF)), MINNF);
    float th = fmaxf(-m, 1.0f + EPSF);
    float arc = arcoshf_(th);
    float dist = fminf(arc, 7.07106781f);                     // sqrt(min(arc^2,50))
    float sc = __fdividef(dist, nu);
    float vx = sc*ux, vy = sc*uy;
    float v0 = sc*u0;
    float v0p = __fdividef(sc*(m - xy) + a0*v0, fmaxf(a0, EPSF));
    accx += (lane == 0) ? v0p : vx;
    accy += vy;
  }

  float u0 = __shfl(accx, 0, 64);
  float md = wredsum(accx*accx + accy*accy) - 2.0f*u0*u0;
  float theta = fmaxf(fminf(sqrtf(fmaxf(md, EPSF)), 1e6f), MINNF);
  float sh, ch; sinhcosh_(theta, sh, ch);
  float s = sh / theta;
  float hx = ch*xv.x + s*accx;
  float hy = ch*xv.y + s*accy;
  float hxm = (lane == 0) ? 0.0f : hx;
  float hh = wredsum(hxm*hxm + hy*hy);
  float h0 = sqrtf(fmaxf(1.0f + hh, EPSF));
  float inv = 1.0f / (h0 + 1.0f);
  float px = fmaxf(hxm*inv, 0.0f);
  float py = fmaxf(hy *inv, 0.0f);
  float sq = wredsum(px*px + py*py);
  float idn = 1.0f / (1.0f - sq);
  float2 o;
  o.x = (lane == 0) ? (1.0f + sq)*idn : 2.0f*px*idn;
  o.y = 2.0f*py*idn;
  *(float2*)&XN[(size_t)wid*128 + lane*2] = o;
}

// ---------------- register-tiled f32 GEMM ----------------
// C[n][j] = sum_c sum_k Ac[n][k] * W[j][c*128+k] (+bias)
// Block: 64 rows x 128 cols, 256 threads, thread tile 8x4, BK=32.
// If S != nullptr (nchunk==1): A row = S[n] * (x row with elem0 zeroed)  [logmap0 fold]
__global__ __launch_bounds__(256) void gemm_k(const float* __restrict__ A0,
                                              const float* __restrict__ A1,
                                              const float* __restrict__ A2,
                                              const float* __restrict__ W,
                                              const float* __restrict__ bias,
                                              const float* __restrict__ S,
                                              float* __restrict__ C, int N, int nchunk){
  __shared__ float Asm[64*32];     // [row][k], ld=32
  __shared__ float Wsm[32*132];    // [k][j] transposed, ld=132
  int tid  = threadIdx.x;
  int base = blockIdx.x * 64;
  int jt   = tid & 31;             // cols jt*4..+3
  int rt   = tid >> 5;             // rows rt*8..+7
  int ldw  = nchunk * 128;
  float acc[8][4];
  #pragma unroll
  for (int i = 0; i < 8; i++)
    #pragma unroll
    for (int jj = 0; jj < 4; jj++) acc[i][jj] = 0.0f;

  for (int c = 0; c < nchunk; ++c){
    const float* Ac = (c == 0) ? A0 : ((c == 1) ? A1 : A2);
    for (int ck = 0; ck < 128; ck += 32){
      // stage A tile: 64 rows x 32 k = 512 float4, 2 per thread
      #pragma unroll
      for (int t = 0; t < 2; ++t){
        int flat = tid + t*256;
        int r = flat >> 3, c4 = flat & 7;
        int node = base + r;
        float4 v = make_float4(0.f,0.f,0.f,0.f);
        if (node < N){
          v = *(const float4*)&Ac[(size_t)node*128 + ck + c4*4];
          if (S){
            float sn = S[node];
            if (ck == 0 && c4 == 0) v.x = 0.0f;
            v.x*=sn; v.y*=sn; v.z*=sn; v.w*=sn;
          }
        }
        *(float4*)&Asm[r*32 + c4*4] = v;
      }
      // stage W transposed: 128 j x 8 k4 = 1024 float4 loads, 4 per thread
      #pragma unroll
      for (int t = 0; t < 4; ++t){
        int flat = tid + t*256;
        int j = flat & 127, k4 = flat >> 7;
        float4 v = *(const float4*)&W[(size_t)j*ldw + c*128 + ck + k4*4];
        Wsm[(k4*4+0)*132 + j] = v.x;
        Wsm[(k4*4+1)*132 + j] = v.y;
        Wsm[(k4*4+2)*132 + j] = v.z;
        Wsm[(k4*4+3)*132 + j] = v.w;
      }
      __syncthreads();
      #pragma unroll
      for (int k4 = 0; k4 < 8; ++k4){
        float4 a[8], w[4];
        #pragma unroll
        for (int i = 0; i < 8; ++i)
          a[i] = *(const float4*)&Asm[(rt*8+i)*32 + k4*4];
        #pragma unroll
        for (int kk = 0; kk < 4; ++kk)
          w[kk] = *(const float4*)&Wsm[(k4*4+kk)*132 + jt*4];
        #pragma unroll
        for (int i = 0; i < 8; ++i){
          acc[i][0] += a[i].x*w[0].x + a[i].y*w[1].x + a[i].z*w[2].x + a[i].w*w[3].x;
          acc[i][1] += a[i].x*w[0].y + a[i].y*w[1].y + a[i].z*w[2].y + a[i].w*w[3].y;
          acc[i][2] += a[i].x*w[0].z + a[i].y*w[1].z + a[i].z*w[2].z + a[i].w*w[3].z;
          acc[i][3] += a[i].x*w[0].w + a[i].y*w[1].w + a[i].z*w[2].w + a[i].w*w[3].w;
        }
      }
      __syncthreads();
    }
  }
  float4 bv = make_float4(0.f,0.f,0.f,0.f);
  if (bias) bv = *(const float4*)&bias[jt*4];
  #pragma unroll
  for (int i = 0; i < 8; ++i){
    int node = base + rt*8 + i;
    if (node < N){
      float4 o;
      o.x = acc[i][0] + bv.x; o.y = acc[i][1] + bv.y;
      o.z = acc[i][2] + bv.z; o.w = acc[i][3] + bv.w;
      *(float4*)&C[(size_t)node*128 + jt*4] = o;
    }
  }
}

extern "C" void kernel_launch(void* const* d_in, const int* in_sizes, int n_in,
                              void* d_out, int out_size, void* d_ws, size_t ws_size,
                              hipStream_t stream) {
  const float* x0 = (const float*)d_in[0];
  const int*   ei = (const int*)  d_in[1];
  const float* W0 = (const float*)d_in[2];
  const float* W1 = (const float*)d_in[3];
  const float* Wf = (const float*)d_in[4];
  const float* bf = (const float*)d_in[5];
  float* out = (float*)d_out;

  int N = in_sizes[0] / 128;
  int E = in_sizes[1] / 2;
  const int* src = ei;
  const int* dst = ei + E;

  size_t row = (size_t)N * 128;
  float* ws = (float*)d_ws;
  float* x1 = ws;                 // conv1 output
  float* x2 = ws + row;           // conv2 output
  float* g  = ws + 2*row;         // gemm out -> expmap0 in-place
  float* Sv = ws + 3*row;         // N floats (logmap0 scale)
  int* rowptr = (int*)(Sv + N);   // N+1
  int* cursor = rowptr + (N + 1); // N (also used as deg)
  int* ssrc   = cursor + N;       // E

  dim3 blk(256);
  int nodeBlocks = (N + 3) / 4;
  int eThreads   = (E + 255) / 256;
  int gemmBlocks = (N + 63) / 64;

  // ---- CSR build (once; shared by both layers) ----
  hipMemsetAsync(cursor, 0, (size_t)N * sizeof(int), stream);
  k_hist<<<eThreads, blk, 0, stream>>>(dst, cursor, E);
  k_scan<<<1, 1024, 0, stream>>>(cursor, rowptr, N);
  hipMemcpyAsync(cursor, rowptr, (size_t)N * sizeof(int),
                 hipMemcpyDeviceToDevice, stream);
  k_scatter<<<eThreads, blk, 0, stream>>>(src, dst, cursor, ssrc, E);

  const float* xin = x0;
  float* xout = x1;
  const float* W = W0;
  for (int l = 0; l < 2; l++){
    k_lognorm<<<nodeBlocks, blk, 0, stream>>>(xin, Sv, N);
    gemm_k  <<<gemmBlocks, blk, 0, stream>>>(xin, nullptr, nullptr, W, nullptr, Sv, g, N, 1);
    k_expmap0<<<nodeBlocks, blk, 0, stream>>>(g, g, N);
    k_conv  <<<nodeBlocks, blk, 0, stream>>>(g, xin, rowptr, ssrc, xout, N);
    xin = xout; xout = x2; W = W1;
  }
  gemm_k<<<gemmBlocks, blk, 0, stream>>>(x0, x1, x2, Wf, bf, nullptr, out, N, 3);
}

// Round 4
// 403.977 us; speedup vs baseline: 3.5188x; 1.6213x over previous
//
#include <hip/hip_runtime.h>
#include <hip/hip_bf16.h>

#define EPSF  1e-7f
#define MINNF 1e-15f

typedef __attribute__((ext_vector_type(8))) short short8v;
typedef __attribute__((ext_vector_type(4))) float f32x4;

__device__ __forceinline__ float wredsum(float v){
  #pragma unroll
  for (int m = 32; m; m >>= 1) v += __shfl_xor(v, m, 64);
  return v;
}

__device__ __forceinline__ float arcoshf_(float x){
  float xc = fmaxf(x, 1.0f);
  return __logf(fmaxf(xc + sqrtf(fmaxf(xc*xc - 1.0f, 0.0f)), MINNF));
}

__device__ __forceinline__ void sinhcosh_(float x, float& sh, float& ch){
  float xc = fminf(fmaxf(x, -15.0f), 15.0f);
  float e  = __expf(xc);
  float ei = 1.0f / e;
  ch = 0.5f * (e + ei);
  sh = 0.5f * (e - ei);
}

__device__ __forceinline__ short f2bf(float f){
  union { __hip_bfloat16 b; short s; } u;
  u.b = __float2bfloat16(f);
  return u.s;
}

__device__ __forceinline__ short8v cvt8(float4 v0, float4 v1){
  short8v h;
  h[0]=f2bf(v0.x); h[1]=f2bf(v0.y); h[2]=f2bf(v0.z); h[3]=f2bf(v0.w);
  h[4]=f2bf(v1.x); h[5]=f2bf(v1.y); h[6]=f2bf(v1.z); h[7]=f2bf(v1.w);
  return h;
}

// ---------------- CSR build ----------------
__global__ __launch_bounds__(256) void k_hist(const int* __restrict__ dst,
                                              int* __restrict__ deg, int E){
  int i = blockIdx.x * blockDim.x + threadIdx.x;
  if (i < E) atomicAdd(&deg[dst[i]], 1);
}

__global__ __launch_bounds__(1024) void k_scan(const int* __restrict__ deg,
                                               int* __restrict__ rowptr, int N){
  __shared__ int wsum[16];
  __shared__ int carry;
  int tid = threadIdx.x, lane = tid & 63, wv = tid >> 6;
  if (tid == 0){ carry = 0; rowptr[0] = 0; }
  __syncthreads();
  for (int bse = 0; bse < N; bse += 1024){
    int i = bse + tid;
    int v = (i < N) ? deg[i] : 0;
    int s = v;
    #pragma unroll
    for (int off = 1; off < 64; off <<= 1){
      int t = __shfl_up(s, off, 64);
      if (lane >= off) s += t;
    }
    if (lane == 63) wsum[wv] = s;
    __syncthreads();
    if (wv == 0){
      int ws = (lane < 16) ? wsum[lane] : 0;
      #pragma unroll
      for (int off = 1; off < 16; off <<= 1){
        int t = __shfl_up(ws, off, 64);
        if (lane >= off) ws += t;
      }
      if (lane < 16) wsum[lane] = ws;
    }
    __syncthreads();
    int incl = s + (wv ? wsum[wv - 1] : 0) + carry;
    if (i < N) rowptr[i + 1] = incl;
    __syncthreads();
    if (tid == 1023) carry = incl;
    __syncthreads();
  }
}

__global__ __launch_bounds__(256) void k_scatter(const int* __restrict__ src,
                                                 const int* __restrict__ dst,
                                                 int* __restrict__ cursor,
                                                 int* __restrict__ ssrc, int E){
  int i = blockIdx.x * blockDim.x + threadIdx.x;
  if (i < E){
    int pos = atomicAdd(&cursor[dst[i]], 1);
    ssrc[pos] = src[i];
  }
}

// ---------------- per-node: s_n = arcosh(theta)/||y||  (layer-0 only) ----------------
__global__ __launch_bounds__(256) void k_lognorm(const float* __restrict__ X,
                                                 float* __restrict__ S, int N){
  int wid  = (blockIdx.x * blockDim.x + threadIdx.x) >> 6;
  int lane = threadIdx.x & 63;
  if (wid >= N) return;
  const float2 xv = *(const float2*)&X[(size_t)wid*128 + lane*2];
  float x0 = __shfl(xv.x, 0, 64);
  float ax = (lane == 0) ? 0.0f : xv.x;
  float yn2 = wredsum(ax*ax + xv.y*xv.y);
  float yn  = fmaxf(sqrtf(yn2), MINNF);
  float theta = fmaxf(x0, 1.0f + EPSF);
  if (lane == 0) S[wid] = arcoshf_(theta) / yn;
}

// ---------------- per-node: out = expmap0(Z) (in-place safe) ----------------
__global__ __launch_bounds__(256) void k_expmap0(const float* __restrict__ Z,
                                                 float* __restrict__ O, int N){
  int wid  = (blockIdx.x * blockDim.x + threadIdx.x) >> 6;
  int lane = threadIdx.x & 63;
  if (wid >= N) return;
  const float2 zv = *(const float2*)&Z[(size_t)wid*128 + lane*2];
  float zx = (lane == 0) ? 0.0f : zv.x;
  float xn2 = wredsum(zx*zx + zv.y*zv.y);
  float xn  = fmaxf(sqrtf(xn2), MINNF);
  float sh, ch; sinhcosh_(xn, sh, ch);
  float s = sh / xn;
  float ox = s * zx;
  float oy = s * zv.y;
  float s2 = wredsum(ox*ox + oy*oy);
  float o0 = sqrtf(fmaxf(1.0f + s2, EPSF));
  if (lane == 0) ox = o0;
  float2 o; o.x = ox; o.y = oy;
  *(float2*)&O[(size_t)wid*128 + lane*2] = o;
}

// ---------------- fused conv: per dst-node register aggregation + expmap/relu/hyperboloid
// Optionally emits S_next = arcosh(theta_out)/||y_out||  (logmap0 scale of the row it just wrote)
__global__ __launch_bounds__(256) void k_conv(const float* __restrict__ OUT,
                                              const float* __restrict__ X,
                                              const int* __restrict__ rowptr,
                                              const int* __restrict__ ssrc,
                                              float* __restrict__ XN,
                                              float* __restrict__ Sout, int N){
  int wid  = (blockIdx.x * blockDim.x + threadIdx.x) >> 6;
  int lane = threadIdx.x & 63;
  if (wid >= N) return;
  const float2 xv = *(const float2*)&X[(size_t)wid*128 + lane*2];
  float b0 = __shfl(xv.x, 0, 64);
  int beg = rowptr[wid], end = rowptr[wid + 1];
  float accx = 0.0f, accy = 0.0f;

  float2 a = make_float2(0.f, 0.f);
  if (beg < end){
    int s0i = ssrc[beg];
    a = *(const float2*)&OUT[(size_t)s0i*128 + lane*2];
  }
  for (int idx = beg; idx < end; ++idx){
    float2 ac = a;
    if (idx + 1 < end){
      int s2 = ssrc[idx + 1];
      a = *(const float2*)&OUT[(size_t)s2*128 + lane*2];   // prefetch next row
    }
    float a0 = __shfl(ac.x, 0, 64);
    float m  = wredsum(ac.x*xv.x + ac.y*xv.y) - 2.0f*a0*b0;   // Minkowski <a,b>
    float xy = fminf(m + 1.0f, -EPSF) - 1.0f;
    float ux = xv.x + xy*ac.x;
    float uy = xv.y + xy*ac.y;
    float u0 = b0   + xy*a0;
    float m_uu = -1.0f + xy*(2.0f*m - xy);
    float nu = fmaxf(sqrtf(fmaxf(m_uu, EPSF)), MINNF);
    float th = fmaxf(-m, 1.0f + EPSF);
    float arc = arcoshf_(th);
    float dist = fminf(arc, 7.07106781f);                     // sqrt(min(arc^2,50))
    float sc = __fdividef(dist, nu);
    float vx = sc*ux, vy = sc*uy;
    float v0 = sc*u0;
    float v0p = __fdividef(sc*(m - xy) + a0*v0, fmaxf(a0, EPSF));
    accx += (lane == 0) ? v0p : vx;
    accy += vy;
  }

  float u0 = __shfl(accx, 0, 64);
  float md = wredsum(accx*accx + accy*accy) - 2.0f*u0*u0;
  float theta = fmaxf(fminf(sqrtf(fmaxf(md, EPSF)), 1e6f), MINNF);
  float sh, ch; sinhcosh_(theta, sh, ch);
  float s = sh / theta;
  float hx = ch*xv.x + s*accx;
  float hy = ch*xv.y + s*accy;
  float hxm = (lane == 0) ? 0.0f : hx;
  float hh = wredsum(hxm*hxm + hy*hy);
  float h0 = sqrtf(fmaxf(1.0f + hh, EPSF));
  float inv = 1.0f / (h0 + 1.0f);
  float px = fmaxf(hxm*inv, 0.0f);
  float py = fmaxf(hy *inv, 0.0f);
  float sq = wredsum(px*px + py*py);
  float idn = 1.0f / (1.0f - sq);
  float2 o;
  o.x = (lane == 0) ? (1.0f + sq)*idn : 2.0f*px*idn;
  o.y = 2.0f*py*idn;
  *(float2*)&XN[(size_t)wid*128 + lane*2] = o;
  if (Sout && lane == 0){
    float o0n   = (1.0f + sq)*idn;
    float ynrm  = fmaxf(2.0f*idn*sqrtf(sq), MINNF);
    float thn   = fmaxf(o0n, 1.0f + EPSF);
    Sout[wid] = arcoshf_(thn) / ynrm;
  }
}

// ---------------- bf16 MFMA GEMM: C[n][j] = sum_c sum_k Ac[n][k]*W[j][c*128+k] (+bias)
// BM=64, BN=128, BK=64; 4 waves (2x2); reg-staged f32->bf16 with XOR-swizzled LDS.
// If S != nullptr (nchunk==1): A row = S[n] * (row with elem0 zeroed)  [logmap0 fold]
__global__ __launch_bounds__(256) void gemm_mfma(const float* __restrict__ A0,
                                                 const float* __restrict__ A1,
                                                 const float* __restrict__ A2,
                                                 const float* __restrict__ W,
                                                 const float* __restrict__ bias,
                                                 const float* __restrict__ S,
                                                 float* __restrict__ C, int N, int nchunk){
  __shared__ short Asm[64*64];    // 64 rows x 64 k bf16, 128 B/row, swizzled
  __shared__ short Wsm[128*64];   // 128 j  x 64 k bf16
  int tid  = threadIdx.x;
  int lane = tid & 63;
  int wid  = tid >> 6;
  int wr   = wid >> 1;            // 0..1: rows wr*32..+31
  int wc   = wid & 1;             // 0..1: cols wc*64..+63
  int base = blockIdx.x * 64;
  int ldw  = nchunk * 128;
  int nkt  = nchunk * 2;

  const f32x4 z4 = {0.f, 0.f, 0.f, 0.f};
  f32x4 acc[2][4];
  #pragma unroll
  for (int mi = 0; mi < 2; ++mi)
    #pragma unroll
    for (int ni = 0; ni < 4; ++ni) acc[mi][ni] = z4;

  for (int kt = 0; kt < nkt; ++kt){
    int ch = kt >> 1;
    const float* Ac = (ch == 0) ? A0 : ((ch == 1) ? A1 : A2);
    int cko = (kt & 1) * 64;
    // stage A: 64x64 elems = 512 groups of 8, 2/thread
    #pragma unroll
    for (int t = 0; t < 2; ++t){
      int g = tid + t*256;
      int r = g >> 3;
      int kc = (g & 7) * 8;
      int node = base + r;
      short8v h = {0,0,0,0,0,0,0,0};
      if (node < N){
        const float* ap = &Ac[(size_t)node*128 + cko + kc];
        float4 v0 = *(const float4*)ap;
        float4 v1 = *(const float4*)(ap + 4);
        if (S){
          float sn = S[node];
          if (cko == 0 && kc == 0) v0.x = 0.0f;
          v0.x*=sn; v0.y*=sn; v0.z*=sn; v0.w*=sn;
          v1.x*=sn; v1.y*=sn; v1.z*=sn; v1.w*=sn;
        }
        h = cvt8(v0, v1);
      }
      int byte = (r*128 + kc*2) ^ ((r & 7) << 4);
      *(short8v*)((char*)Asm + byte) = h;
    }
    // stage W: 128x64 elems = 1024 groups, 4/thread
    #pragma unroll
    for (int t = 0; t < 4; ++t){
      int g = tid + t*256;
      int j = g >> 3;
      int kc = (g & 7) * 8;
      const float* wp = &W[(size_t)j*ldw + kt*64 + kc];
      float4 v0 = *(const float4*)wp;
      float4 v1 = *(const float4*)(wp + 4);
      short8v h = cvt8(v0, v1);
      int byte = (j*128 + kc*2) ^ ((j & 7) << 4);
      *(short8v*)((char*)Wsm + byte) = h;
    }
    __syncthreads();
    #pragma unroll
    for (int ks = 0; ks < 2; ++ks){
      int kb = ks*64 + (lane >> 4) * 16;          // byte offset in row
      short8v af[2], bfv[4];
      #pragma unroll
      for (int mi = 0; mi < 2; ++mi){
        int r = wr*32 + mi*16 + (lane & 15);
        af[mi] = *(const short8v*)((const char*)Asm + ((r*128 + kb) ^ ((r & 7) << 4)));
      }
      #pragma unroll
      for (int ni = 0; ni < 4; ++ni){
        int j = wc*64 + ni*16 + (lane & 15);
        bfv[ni] = *(const short8v*)((const char*)Wsm + ((j*128 + kb) ^ ((j & 7) << 4)));
      }
      #pragma unroll
      for (int mi = 0; mi < 2; ++mi)
        #pragma unroll
        for (int ni = 0; ni < 4; ++ni)
          acc[mi][ni] = __builtin_amdgcn_mfma_f32_16x16x32_bf16(af[mi], bfv[ni], acc[mi][ni], 0, 0, 0);
    }
    __syncthreads();
  }
  // epilogue: C row = (lane>>4)*4 + reg, col = lane&15 within each 16x16 frag
  #pragma unroll
  for (int mi = 0; mi < 2; ++mi){
    #pragma unroll
    for (int rg = 0; rg < 4; ++rg){
      int row = base + wr*32 + mi*16 + (lane >> 4)*4 + rg;
      if (row < N){
        #pragma unroll
        for (int ni = 0; ni < 4; ++ni){
          int col = wc*64 + ni*16 + (lane & 15);
          float v = acc[mi][ni][rg];
          if (bias) v += bias[col];
          C[(size_t)row*128 + col] = v;
        }
      }
    }
  }
}

extern "C" void kernel_launch(void* const* d_in, const int* in_sizes, int n_in,
                              void* d_out, int out_size, void* d_ws, size_t ws_size,
                              hipStream_t stream) {
  const float* x0 = (const float*)d_in[0];
  const int*   ei = (const int*)  d_in[1];
  const float* W0 = (const float*)d_in[2];
  const float* W1 = (const float*)d_in[3];
  const float* Wf = (const float*)d_in[4];
  const float* bf = (const float*)d_in[5];
  float* out = (float*)d_out;

  int N = in_sizes[0] / 128;
  int E = in_sizes[1] / 2;
  const int* src = ei;
  const int* dst = ei + E;

  size_t row = (size_t)N * 128;
  float* ws = (float*)d_ws;
  float* x1 = ws;                 // conv1 output
  float* x2 = ws + row;           // conv2 output
  float* g  = ws + 2*row;         // gemm out -> expmap0 in-place
  float* Sv = ws + 3*row;         // N floats (logmap0 scale)
  int* rowptr = (int*)(Sv + N);   // N+1
  int* cursor = rowptr + (N + 1); // N (also deg)
  int* ssrc   = cursor + N;       // E

  dim3 blk(256);
  int nodeBlocks = (N + 3) / 4;
  int eThreads   = (E + 255) / 256;
  int gemmBlocks = (N + 63) / 64;

  // ---- CSR build (once; shared by both layers) ----
  hipMemsetAsync(cursor, 0, (size_t)N * sizeof(int), stream);
  k_hist<<<eThreads, blk, 0, stream>>>(dst, cursor, E);
  k_scan<<<1, 1024, 0, stream>>>(cursor, rowptr, N);
  hipMemcpyAsync(cursor, rowptr, (size_t)N * sizeof(int),
                 hipMemcpyDeviceToDevice, stream);
  k_scatter<<<eThreads, blk, 0, stream>>>(src, dst, cursor, ssrc, E);

  // ---- layer 0 ----
  k_lognorm <<<nodeBlocks, blk, 0, stream>>>(x0, Sv, N);
  gemm_mfma <<<gemmBlocks, blk, 0, stream>>>(x0, nullptr, nullptr, W0, nullptr, Sv, g, N, 1);
  k_expmap0 <<<nodeBlocks, blk, 0, stream>>>(g, g, N);
  k_conv    <<<nodeBlocks, blk, 0, stream>>>(g, x0, rowptr, ssrc, x1, Sv, N);  // Sv = lognorm(x1)

  // ---- layer 1 ----
  gemm_mfma <<<gemmBlocks, blk, 0, stream>>>(x1, nullptr, nullptr, W1, nullptr, Sv, g, N, 1);
  k_expmap0 <<<nodeBlocks, blk, 0, stream>>>(g, g, N);
  k_conv    <<<nodeBlocks, blk, 0, stream>>>(g, x1, rowptr, ssrc, x2, nullptr, N);

  // ---- final fused GEMM ----
  gemm_mfma <<<gemmBlocks, blk, 0, stream>>>(x0, x1, x2, Wf, bf, nullptr, out, N, 3);
}

// Round 5
// 347.067 us; speedup vs baseline: 4.0958x; 1.1640x over previous
//
#include <hip/hip_runtime.h>
#include <hip/hip_bf16.h>

#define EPSF  1e-7f
#define MINNF 1e-15f

typedef __attribute__((ext_vector_type(8))) short short8v;
typedef __attribute__((ext_vector_type(4))) float f32x4;

__device__ __forceinline__ float wredsum(float v){
  #pragma unroll
  for (int m = 32; m; m >>= 1) v += __shfl_xor(v, m, 64);
  return v;
}

__device__ __forceinline__ float hredsum(float v){   // within 32-lane half
  #pragma unroll
  for (int m = 16; m; m >>= 1) v += __shfl_xor(v, m, 64);
  return v;
}

__device__ __forceinline__ float arcoshf_(float x){
  float xc = fmaxf(x, 1.0f);
  return __logf(fmaxf(xc + sqrtf(fmaxf(xc*xc - 1.0f, 0.0f)), MINNF));
}

__device__ __forceinline__ void sinhcosh_(float x, float& sh, float& ch){
  float xc = fminf(fmaxf(x, -15.0f), 15.0f);
  float e  = __expf(xc);
  float ei = 1.0f / e;
  ch = 0.5f * (e + ei);
  sh = 0.5f * (e - ei);
}

__device__ __forceinline__ short f2bf(float f){
  union { __hip_bfloat16 b; short s; } u;
  u.b = __float2bfloat16(f);
  return u.s;
}

__device__ __forceinline__ short8v cvt8(float4 v0, float4 v1){
  short8v h;
  h[0]=f2bf(v0.x); h[1]=f2bf(v0.y); h[2]=f2bf(v0.z); h[3]=f2bf(v0.w);
  h[4]=f2bf(v1.x); h[5]=f2bf(v1.y); h[6]=f2bf(v1.z); h[7]=f2bf(v1.w);
  return h;
}

// ---------------- CSR build ----------------
__global__ __launch_bounds__(256) void k_hist(const int* __restrict__ dst,
                                              int* __restrict__ deg, int E){
  int i = blockIdx.x * blockDim.x + threadIdx.x;
  if (i < E) atomicAdd(&deg[dst[i]], 1);
}

__global__ __launch_bounds__(1024) void k_scan(const int* __restrict__ deg,
                                               int* __restrict__ rowptr, int N){
  __shared__ int wsum[16];
  __shared__ int carry;
  int tid = threadIdx.x, lane = tid & 63, wv = tid >> 6;
  if (tid == 0){ carry = 0; rowptr[0] = 0; }
  __syncthreads();
  for (int bse = 0; bse < N; bse += 1024){
    int i = bse + tid;
    int v = (i < N) ? deg[i] : 0;
    int s = v;
    #pragma unroll
    for (int off = 1; off < 64; off <<= 1){
      int t = __shfl_up(s, off, 64);
      if (lane >= off) s += t;
    }
    if (lane == 63) wsum[wv] = s;
    __syncthreads();
    if (wv == 0){
      int ws = (lane < 16) ? wsum[lane] : 0;
      #pragma unroll
      for (int off = 1; off < 16; off <<= 1){
        int t = __shfl_up(ws, off, 64);
        if (lane >= off) ws += t;
      }
      if (lane < 16) wsum[lane] = ws;
    }
    __syncthreads();
    int incl = s + (wv ? wsum[wv - 1] : 0) + carry;
    if (i < N) rowptr[i + 1] = incl;
    __syncthreads();
    if (tid == 1023) carry = incl;
    __syncthreads();
  }
}

__global__ __launch_bounds__(256) void k_scatter(const int* __restrict__ src,
                                                 const int* __restrict__ dst,
                                                 int* __restrict__ cursor,
                                                 int* __restrict__ ssrc, int E){
  int i = blockIdx.x * blockDim.x + threadIdx.x;
  if (i < E){
    int pos = atomicAdd(&cursor[dst[i]], 1);
    ssrc[pos] = src[i];
  }
}

// ---------------- per-node: s_n = arcosh(theta)/||y||  (layer-0 only) ----------------
__global__ __launch_bounds__(256) void k_lognorm(const float* __restrict__ X,
                                                 float* __restrict__ S, int N){
  int wid  = (blockIdx.x * blockDim.x + threadIdx.x) >> 6;
  int lane = threadIdx.x & 63;
  if (wid >= N) return;
  const float2 xv = *(const float2*)&X[(size_t)wid*128 + lane*2];
  float x0 = __shfl(xv.x, 0, 64);
  float ax = (lane == 0) ? 0.0f : xv.x;
  float yn2 = wredsum(ax*ax + xv.y*xv.y);
  float yn  = fmaxf(sqrtf(yn2), MINNF);
  float theta = fmaxf(x0, 1.0f + EPSF);
  if (lane == 0) S[wid] = arcoshf_(theta) / yn;
}

// ---------------- fused conv: 2 edges/wave (32-lane halves, float4/lane) ----------------
__global__ __launch_bounds__(256) void k_conv(const float* __restrict__ OUT,
                                              const float* __restrict__ X,
                                              const int* __restrict__ rowptr,
                                              const int* __restrict__ ssrc,
                                              float* __restrict__ XN,
                                              float* __restrict__ Sout, int N){
  int node = (blockIdx.x * blockDim.x + threadIdx.x) >> 6;
  int lane = threadIdx.x & 63;
  int half = lane >> 5;
  int l32  = lane & 31;
  if (node >= N) return;
  const float4 xv = *(const float4*)&X[(size_t)node*128 + l32*4];
  float b0 = __shfl(xv.x, 0, 64);
  int beg = rowptr[node], end = rowptr[node + 1];
  float acc0 = 0.f, acc1 = 0.f, acc2 = 0.f, acc3 = 0.f;

  int idx = beg + half;
  bool cur_ok = (idx < end);
  float4 a = make_float4(0.f,0.f,0.f,0.f);
  if (cur_ok){
    int s0 = ssrc[idx];
    a = *(const float4*)&OUT[(size_t)s0*128 + l32*4];
  }
  for (int it = beg; it < end; it += 2){
    float4 ac = a;
    bool ok = cur_ok;
    idx += 2;
    cur_ok = (idx < end);
    if (cur_ok){
      int s2 = ssrc[idx];
      a = *(const float4*)&OUT[(size_t)s2*128 + l32*4];    // prefetch next pair
    }
    float a0 = __shfl(ac.x, half << 5, 64);                 // elem0 of this half's row
    float dp = ac.x*xv.x + ac.y*xv.y + ac.z*xv.z + ac.w*xv.w;
    dp = hredsum(dp);
    float m  = dp - 2.0f*a0*b0;                             // Minkowski <a,b>
    float xy = fminf(m + 1.0f, -EPSF) - 1.0f;
    float m_uu = -1.0f + xy*(2.0f*m - xy);
    float nu = fmaxf(sqrtf(fmaxf(m_uu, EPSF)), MINNF);
    float th = fmaxf(-m, 1.0f + EPSF);
    float arc = arcoshf_(th);
    float dist = fminf(arc, 7.07106781f);                   // sqrt(min(arc^2,50))
    float sc = __fdividef(dist, nu);
    float u0 = b0 + xy*a0;
    float v0 = sc*u0;
    float v0p = __fdividef(sc*(m - xy) + a0*v0, fmaxf(a0, EPSF));
    float vx = sc*(xv.x + xy*ac.x);
    if (l32 == 0) vx = v0p;                                 // time component
    if (ok){
      acc0 += vx;
      acc1 += sc*(xv.y + xy*ac.y);
      acc2 += sc*(xv.z + xy*ac.z);
      acc3 += sc*(xv.w + xy*ac.w);
    }
  }
  // fold halves
  acc0 += __shfl_xor(acc0, 32, 64);
  acc1 += __shfl_xor(acc1, 32, 64);
  acc2 += __shfl_xor(acc2, 32, 64);
  acc3 += __shfl_xor(acc3, 32, 64);

  // expmap(aggr, x) + relu(poincare) + to_hyperboloid  (32-lane layout, halves duplicated)
  float u0 = __shfl(acc0, 0, 64);
  float md = hredsum(acc0*acc0 + acc1*acc1 + acc2*acc2 + acc3*acc3) - 2.0f*u0*u0;
  float theta = fmaxf(fminf(sqrtf(fmaxf(md, EPSF)), 1e6f), MINNF);
  float sh, ch; sinhcosh_(theta, sh, ch);
  float s = sh / theta;
  float h0x = ch*xv.x + s*acc0;
  float h1 = ch*xv.y + s*acc1;
  float h2 = ch*xv.z + s*acc2;
  float h3 = ch*xv.w + s*acc3;
  float hxm = (l32 == 0) ? 0.0f : h0x;                      // proj drops elem0
  float hh = hredsum(hxm*hxm + h1*h1 + h2*h2 + h3*h3);
  float hf = sqrtf(fmaxf(1.0f + hh, EPSF));
  float inv = 1.0f / (hf + 1.0f);
  float p0 = fmaxf(hxm*inv, 0.0f);
  float p1 = fmaxf(h1*inv, 0.0f);
  float p2 = fmaxf(h2*inv, 0.0f);
  float p3 = fmaxf(h3*inv, 0.0f);
  float sq = hredsum(p0*p0 + p1*p1 + p2*p2 + p3*p3);
  float idn = 1.0f / (1.0f - sq);
  float4 o;
  o.x = (l32 == 0) ? (1.0f + sq)*idn : 2.0f*p0*idn;
  o.y = 2.0f*p1*idn;
  o.z = 2.0f*p2*idn;
  o.w = 2.0f*p3*idn;
  if (half == 0)
    *(float4*)&XN[(size_t)node*128 + l32*4] = o;
  if (Sout && lane == 0){
    float o0n  = (1.0f + sq)*idn;
    float ynrm = fmaxf(2.0f*idn*sqrtf(sq), MINNF);
    float thn  = fmaxf(o0n, 1.0f + EPSF);
    Sout[node] = arcoshf_(thn) / ynrm;
  }
}

// ---------------- bf16 MFMA GEMM (+ optional fused expmap0 epilogue) ----------------
// C[n][j] = sum_c sum_k Ac[n][k]*W[j][c*128+k] (+bias)
// BM=64, BN=128, BK=64; 4 waves (2x2); reg-staged f32->bf16 with XOR-swizzled LDS.
// If S != nullptr (nchunk==1): A row = S[n] * (row with elem0 zeroed)  [logmap0 fold]
// If DO_EXP: apply expmap0 row-wise via LDS before the global write.
template<int DO_EXP>
__global__ __launch_bounds__(256) void gemm_mfma(const float* __restrict__ A0,
                                                 const float* __restrict__ A1,
                                                 const float* __restrict__ A2,
                                                 const float* __restrict__ W,
                                                 const float* __restrict__ bias,
                                                 const float* __restrict__ S,
                                                 float* __restrict__ C, int N, int nchunk){
  __shared__ __align__(16) char smraw[64*130*4];            // 33.3 KB (union)
  short* Asm = (short*)smraw;                               // 64x64 bf16 swizzled
  short* Wsm = Asm + 64*64;                                 // 128x64 bf16 swizzled
  float* Csm = (float*)smraw;                               // 64x130 f32 (epilogue)
  int tid  = threadIdx.x;
  int lane = tid & 63;
  int wid  = tid >> 6;
  int wr   = wid >> 1;
  int wc   = wid & 1;
  int base = blockIdx.x * 64;
  int ldw  = nchunk * 128;
  int nkt  = nchunk * 2;

  const f32x4 z4 = {0.f, 0.f, 0.f, 0.f};
  f32x4 acc[2][4];
  #pragma unroll
  for (int mi = 0; mi < 2; ++mi)
    #pragma unroll
    for (int ni = 0; ni < 4; ++ni) acc[mi][ni] = z4;

  for (int kt = 0; kt < nkt; ++kt){
    int ch = kt >> 1;
    const float* Ac = (ch == 0) ? A0 : ((ch == 1) ? A1 : A2);
    int cko = (kt & 1) * 64;
    #pragma unroll
    for (int t = 0; t < 2; ++t){
      int g = tid + t*256;
      int r = g >> 3;
      int kc = (g & 7) * 8;
      int nd = base + r;
      short8v h = {0,0,0,0,0,0,0,0};
      if (nd < N){
        const float* ap = &Ac[(size_t)nd*128 + cko + kc];
        float4 v0 = *(const float4*)ap;
        float4 v1 = *(const float4*)(ap + 4);
        if (S){
          float sn = S[nd];
          if (cko == 0 && kc == 0) v0.x = 0.0f;
          v0.x*=sn; v0.y*=sn; v0.z*=sn; v0.w*=sn;
          v1.x*=sn; v1.y*=sn; v1.z*=sn; v1.w*=sn;
        }
        h = cvt8(v0, v1);
      }
      int byte = (r*128 + kc*2) ^ ((r & 7) << 4);
      *(short8v*)((char*)Asm + byte) = h;
    }
    #pragma unroll
    for (int t = 0; t < 4; ++t){
      int g = tid + t*256;
      int j = g >> 3;
      int kc = (g & 7) * 8;
      const float* wp = &W[(size_t)j*ldw + kt*64 + kc];
      float4 v0 = *(const float4*)wp;
      float4 v1 = *(const float4*)(wp + 4);
      short8v h = cvt8(v0, v1);
      int byte = (j*128 + kc*2) ^ ((j & 7) << 4);
      *(short8v*)((char*)Wsm + byte) = h;
    }
    __syncthreads();
    #pragma unroll
    for (int ks = 0; ks < 2; ++ks){
      int kb = ks*64 + (lane >> 4) * 16;
      short8v af[2], bfv[4];
      #pragma unroll
      for (int mi = 0; mi < 2; ++mi){
        int r = wr*32 + mi*16 + (lane & 15);
        af[mi] = *(const short8v*)((const char*)Asm + ((r*128 + kb) ^ ((r & 7) << 4)));
      }
      #pragma unroll
      for (int ni = 0; ni < 4; ++ni){
        int j = wc*64 + ni*16 + (lane & 15);
        bfv[ni] = *(const short8v*)((const char*)Wsm + ((j*128 + kb) ^ ((j & 7) << 4)));
      }
      #pragma unroll
      for (int mi = 0; mi < 2; ++mi)
        #pragma unroll
        for (int ni = 0; ni < 4; ++ni)
          acc[mi][ni] = __builtin_amdgcn_mfma_f32_16x16x32_bf16(af[mi], bfv[ni], acc[mi][ni], 0, 0, 0);
    }
    __syncthreads();
  }

  if (DO_EXP){
    // stage C tile -> LDS (ld=130 to stagger banks), then row-wise expmap0
    #pragma unroll
    for (int mi = 0; mi < 2; ++mi)
      #pragma unroll
      for (int rg = 0; rg < 4; ++rg){
        int r = wr*32 + mi*16 + (lane >> 4)*4 + rg;
        #pragma unroll
        for (int ni = 0; ni < 4; ++ni){
          int col = wc*64 + ni*16 + (lane & 15);
          Csm[r*130 + col] = acc[mi][ni][rg];
        }
      }
    __syncthreads();
    for (int rr = 0; rr < 16; ++rr){
      int r = wid*16 + rr;
      int nd = base + r;
      if (nd >= N) continue;
      float2 zv = *(const float2*)&Csm[r*130 + lane*2];
      float zx = (lane == 0) ? 0.0f : zv.x;
      float xn2 = wredsum(zx*zx + zv.y*zv.y);
      float xn  = fmaxf(sqrtf(xn2), MINNF);
      float sh, chh; sinhcosh_(xn, sh, chh);
      float s = sh / xn;
      float ox = s * zx;
      float oy = s * zv.y;
      float s2 = wredsum(ox*ox + oy*oy);
      float o0 = sqrtf(fmaxf(1.0f + s2, EPSF));
      if (lane == 0) ox = o0;
      float2 o; o.x = ox; o.y = oy;
      *(float2*)&C[(size_t)nd*128 + lane*2] = o;
    }
  } else {
    #pragma unroll
    for (int mi = 0; mi < 2; ++mi){
      #pragma unroll
      for (int rg = 0; rg < 4; ++rg){
        int row = base + wr*32 + mi*16 + (lane >> 4)*4 + rg;
        if (row < N){
          #pragma unroll
          for (int ni = 0; ni < 4; ++ni){
            int col = wc*64 + ni*16 + (lane & 15);
            float v = acc[mi][ni][rg];
            if (bias) v += bias[col];
            C[(size_t)row*128 + col] = v;
          }
        }
      }
    }
  }
}

extern "C" void kernel_launch(void* const* d_in, const int* in_sizes, int n_in,
                              void* d_out, int out_size, void* d_ws, size_t ws_size,
                              hipStream_t stream) {
  const float* x0 = (const float*)d_in[0];
  const int*   ei = (const int*)  d_in[1];
  const float* W0 = (const float*)d_in[2];
  const float* W1 = (const float*)d_in[3];
  const float* Wf = (const float*)d_in[4];
  const float* bf = (const float*)d_in[5];
  float* out = (float*)d_out;

  int N = in_sizes[0] / 128;
  int E = in_sizes[1] / 2;
  const int* src = ei;
  const int* dst = ei + E;

  size_t row = (size_t)N * 128;
  float* ws = (float*)d_ws;
  float* x1 = ws;                 // conv1 output
  float* x2 = ws + row;           // conv2 output
  float* g  = ws + 2*row;         // gemm+expmap0 output (conv input)
  float* Sv = ws + 3*row;         // N floats (logmap0 scale)
  int* rowptr = (int*)(Sv + N);   // N+1
  int* cursor = rowptr + (N + 1); // N (also deg)
  int* ssrc   = cursor + N;       // E

  dim3 blk(256);
  int nodeBlocks = (N + 3) / 4;
  int eThreads   = (E + 255) / 256;
  int gemmBlocks = (N + 63) / 64;

  // ---- CSR build (once; shared by both layers) ----
  hipMemsetAsync(cursor, 0, (size_t)N * sizeof(int), stream);
  k_hist<<<eThreads, blk, 0, stream>>>(dst, cursor, E);
  k_scan<<<1, 1024, 0, stream>>>(cursor, rowptr, N);
  hipMemcpyAsync(cursor, rowptr, (size_t)N * sizeof(int),
                 hipMemcpyDeviceToDevice, stream);
  k_scatter<<<eThreads, blk, 0, stream>>>(src, dst, cursor, ssrc, E);

  // ---- layer 0 ----
  k_lognorm    <<<nodeBlocks, blk, 0, stream>>>(x0, Sv, N);
  gemm_mfma<1> <<<gemmBlocks, blk, 0, stream>>>(x0, nullptr, nullptr, W0, nullptr, Sv, g, N, 1);
  k_conv       <<<nodeBlocks, blk, 0, stream>>>(g, x0, rowptr, ssrc, x1, Sv, N);  // Sv = lognorm(x1)

  // ---- layer 1 ----
  gemm_mfma<1> <<<gemmBlocks, blk, 0, stream>>>(x1, nullptr, nullptr, W1, nullptr, Sv, g, N, 1);
  k_conv       <<<nodeBlocks, blk, 0, stream>>>(g, x1, rowptr, ssrc, x2, nullptr, N);

  // ---- final fused GEMM ----
  gemm_mfma<0> <<<gemmBlocks, blk, 0, stream>>>(x0, x1, x2, Wf, bf, nullptr, out, N, 3);
}

// Round 6
// 276.473 us; speedup vs baseline: 5.1416x; 1.2553x over previous
//
#include <hip/hip_runtime.h>
#include <hip/hip_bf16.h>

#define EPSF  1e-7f
#define MINNF 1e-15f

typedef __attribute__((ext_vector_type(8))) short short8v;
typedef __attribute__((ext_vector_type(8))) unsigned short ushort8v;
typedef __attribute__((ext_vector_type(4))) float f32x4;

__device__ __forceinline__ float wredsum(float v){
  #pragma unroll
  for (int m = 32; m; m >>= 1) v += __shfl_xor(v, m, 64);
  return v;
}

__device__ __forceinline__ float arcoshf_(float x){
  float xc = fmaxf(x, 1.0f);
  return __logf(fmaxf(xc + sqrtf(fmaxf(xc*xc - 1.0f, 0.0f)), MINNF));
}

__device__ __forceinline__ void sinhcosh_(float x, float& sh, float& ch){
  float xc = fminf(fmaxf(x, -15.0f), 15.0f);
  float e  = __expf(xc);
  float ei = 1.0f / e;
  ch = 0.5f * (e + ei);
  sh = 0.5f * (e - ei);
}

__device__ __forceinline__ short f2bf(float f){
  union { __hip_bfloat16 b; short s; } u;
  u.b = __float2bfloat16(f);
  return u.s;
}

__device__ __forceinline__ float bf2f(unsigned short u){
  union { unsigned int i; float f; } c;
  c.i = ((unsigned int)u) << 16;
  return c.f;
}

__device__ __forceinline__ short8v cvt8(float4 v0, float4 v1){
  short8v h;
  h[0]=f2bf(v0.x); h[1]=f2bf(v0.y); h[2]=f2bf(v0.z); h[3]=f2bf(v0.w);
  h[4]=f2bf(v1.x); h[5]=f2bf(v1.y); h[6]=f2bf(v1.z); h[7]=f2bf(v1.w);
  return h;
}

// ---------------- CSR build ----------------
__global__ __launch_bounds__(256) void k_hist(const int* __restrict__ dst,
                                              int* __restrict__ deg, int E){
  int i = blockIdx.x * blockDim.x + threadIdx.x;
  if (i < E) atomicAdd(&deg[dst[i]], 1);
}

// per-block inclusive scan of 256 elems; writes rowptr[i+1] (pre-offset) + block total
__global__ __launch_bounds__(256) void k_blockscan(const int* __restrict__ deg,
                                                   int* __restrict__ rowptr,
                                                   int* __restrict__ partials, int N){
  __shared__ int wtot[4];
  int tid = threadIdx.x, lane = tid & 63, wv = tid >> 6;
  int i = blockIdx.x * 256 + tid;
  int v = (i < N) ? deg[i] : 0;
  int s = v;
  #pragma unroll
  for (int off = 1; off < 64; off <<= 1){
    int t = __shfl_up(s, off, 64);
    if (lane >= off) s += t;
  }
  if (lane == 63) wtot[wv] = s;
  __syncthreads();
  int add = 0;
  #pragma unroll
  for (int w = 0; w < 4; ++w) add += (w < wv) ? wtot[w] : 0;
  s += add;
  if (i < N) rowptr[i + 1] = s;
  if (tid == 255) partials[blockIdx.x] = s;
}

// single-block inclusive scan of up to 256*chunks partials (serial over chunks)
__global__ __launch_bounds__(256) void k_scanpart(int* __restrict__ partials, int nb){
  __shared__ int sm[256];
  __shared__ int carry;
  int t = threadIdx.x;
  if (t == 0) carry = 0;
  __syncthreads();
  for (int base = 0; base < nb; base += 256){
    int i = base + t;
    int v = (i < nb) ? partials[i] : 0;
    sm[t] = v;
    __syncthreads();
    for (int off = 1; off < 256; off <<= 1){
      int x = (t >= off) ? sm[t - off] : 0;
      __syncthreads();
      sm[t] += x;
      __syncthreads();
    }
    int incl = sm[t] + carry;
    if (i < nb) partials[i] = incl;
    __syncthreads();
    if (t == 255) carry = incl;
    __syncthreads();
  }
}

// add block offsets; finalize rowptr and fill cursor (= rowptr[0..N-1])
__global__ __launch_bounds__(256) void k_addoff(const int* __restrict__ partials,
                                                int* __restrict__ rowptr,
                                                int* __restrict__ cursor, int N){
  int i = blockIdx.x * 256 + threadIdx.x;
  int off = (blockIdx.x > 0) ? partials[blockIdx.x - 1] : 0;
  if (i == 0){ rowptr[0] = 0; cursor[0] = 0; }
  if (i < N){
    int vfull = rowptr[i + 1] + off;
    rowptr[i + 1] = vfull;
    if (i + 1 < N) cursor[i + 1] = vfull;
  }
}

__global__ __launch_bounds__(256) void k_scatter(const int* __restrict__ src,
                                                 const int* __restrict__ dst,
                                                 int* __restrict__ cursor,
                                                 int* __restrict__ ssrc, int E){
  int i = blockIdx.x * blockDim.x + threadIdx.x;
  if (i < E){
    int pos = atomicAdd(&cursor[dst[i]], 1);
    ssrc[pos] = src[i];
  }
}

// ---------------- per-node: s_n = arcosh(theta)/||y||  (layer-0 only) ----------------
__global__ __launch_bounds__(256) void k_lognorm(const float* __restrict__ X,
                                                 float* __restrict__ S, int N){
  int wid  = (blockIdx.x * blockDim.x + threadIdx.x) >> 6;
  int lane = threadIdx.x & 63;
  if (wid >= N) return;
  const float2 xv = *(const float2*)&X[(size_t)wid*128 + lane*2];
  float x0 = __shfl(xv.x, 0, 64);
  float ax = (lane == 0) ? 0.0f : xv.x;
  float yn2 = wredsum(ax*ax + xv.y*xv.y);
  float yn  = fmaxf(sqrtf(yn2), MINNF);
  float theta = fmaxf(x0, 1.0f + EPSF);
  if (lane == 0) S[wid] = arcoshf_(theta) / yn;
}

// ---------------- fused conv: 4 edges/wave (16-lane groups), factored message sum ----------------
// msg_e = sc_e*(b + xy_e*a_e)  =>  aggr = alpha*b + sum(gamma_e*a_e), alpha=sum sc, gamma=sc*xy
// time component replaced per-edge by v0p (proj_tan), accumulated as scalar acc0s.
__global__ __launch_bounds__(256) void k_conv(const unsigned short* __restrict__ OUT,
                                              const float* __restrict__ X,
                                              const int* __restrict__ rowptr,
                                              const int* __restrict__ ssrc,
                                              float* __restrict__ XN,
                                              float* __restrict__ Sout, int N){
  int node  = (blockIdx.x * blockDim.x + threadIdx.x) >> 6;
  int lane  = threadIdx.x & 63;
  int gbase = lane & 48;          // group base lane
  int l16   = lane & 15;
  if (node >= N) return;
  float x[8];
  {
    const float4 xlo = *(const float4*)&X[(size_t)node*128 + l16*8];
    const float4 xhi = *(const float4*)&X[(size_t)node*128 + l16*8 + 4];
    x[0]=xlo.x; x[1]=xlo.y; x[2]=xlo.z; x[3]=xlo.w;
    x[4]=xhi.x; x[5]=xhi.y; x[6]=xhi.z; x[7]=xhi.w;
  }
  float b0 = __shfl(x[0], gbase, 64);
  int beg = rowptr[node], end = rowptr[node + 1];
  float accA[8] = {0,0,0,0,0,0,0,0};
  float alpha = 0.f, acc0s = 0.f;

  int idx = beg + (gbase >> 4);
  bool okn = (idx < end);
  ushort8v araw = {0,0,0,0,0,0,0,0};
  if (okn) araw = *(const ushort8v*)&OUT[(size_t)ssrc[idx]*128 + l16*8];
  for (int it = beg; it < end; it += 4){
    ushort8v cur = araw;
    bool okc = okn;
    idx += 4; okn = (idx < end);
    if (okn) araw = *(const ushort8v*)&OUT[(size_t)ssrc[idx]*128 + l16*8];  // prefetch
    float a[8];
    #pragma unroll
    for (int j = 0; j < 8; ++j) a[j] = bf2f(cur[j]);
    float a0 = __shfl(a[0], gbase, 64);
    float dp = a[0]*x[0];
    #pragma unroll
    for (int j = 1; j < 8; ++j) dp = fmaf(a[j], x[j], dp);
    #pragma unroll
    for (int mm = 1; mm < 16; mm <<= 1) dp += __shfl_xor(dp, mm, 64);
    float m  = dp - 2.0f*a0*b0;                         // Minkowski <a,b>
    float xy = fminf(m + 1.0f, -EPSF) - 1.0f;
    float m_uu = -1.0f + xy*(2.0f*m - xy);              // <p,p>=-1 identity
    float nu = fmaxf(sqrtf(fmaxf(m_uu, EPSF)), MINNF);
    float th = fmaxf(-m, 1.0f + EPSF);
    float arc = arcoshf_(th);
    float dist = fminf(arc, 7.07106781f);               // sqrt(min(arc^2,50))
    float sc = __fdividef(dist, nu);
    float u0 = b0 + xy*a0;
    float v0 = sc*u0;
    float v0p = __fdividef(fmaf(sc, m - xy, a0*v0), fmaxf(a0, EPSF));
    float gam = okc ? sc*xy : 0.f;
    alpha += okc ? sc  : 0.f;
    acc0s += okc ? v0p : 0.f;
    #pragma unroll
    for (int j = 0; j < 8; ++j) accA[j] = fmaf(gam, a[j], accA[j]);
  }
  // fold the 4 groups
  #pragma unroll
  for (int j = 0; j < 8; ++j){
    accA[j] += __shfl_xor(accA[j], 16, 64);
    accA[j] += __shfl_xor(accA[j], 32, 64);
  }
  alpha += __shfl_xor(alpha, 16, 64); alpha += __shfl_xor(alpha, 32, 64);
  acc0s += __shfl_xor(acc0s, 16, 64); acc0s += __shfl_xor(acc0s, 32, 64);

  float acc[8];
  #pragma unroll
  for (int j = 0; j < 8; ++j) acc[j] = fmaf(alpha, x[j], accA[j]);
  if (l16 == 0) acc[0] = acc0s;          // time component
  float u0 = acc0s;

  // expmap(aggr, x) + relu(poincare) + to_hyperboloid  (16-lane groups, 4x redundant)
  float md = 0.f;
  #pragma unroll
  for (int j = 0; j < 8; ++j) md = fmaf(acc[j], acc[j], md);
  #pragma unroll
  for (int mm = 1; mm < 16; mm <<= 1) md += __shfl_xor(md, mm, 64);
  md -= 2.0f*u0*u0;
  float theta = fmaxf(fminf(sqrtf(fmaxf(md, EPSF)), 1e6f), MINNF);
  float sh, ch; sinhcosh_(theta, sh, ch);
  float s = __fdividef(sh, theta);
  float h[8];
  #pragma unroll
  for (int j = 0; j < 8; ++j) h[j] = ch*x[j] + s*acc[j];
  if (l16 == 0) h[0] = 0.f;              // proj drops elem0
  float hh = 0.f;
  #pragma unroll
  for (int j = 0; j < 8; ++j) hh = fmaf(h[j], h[j], hh);
  #pragma unroll
  for (int mm = 1; mm < 16; mm <<= 1) hh += __shfl_xor(hh, mm, 64);
  float h0 = sqrtf(fmaxf(1.0f + hh, EPSF));
  float inv = 1.0f / (h0 + 1.0f);
  float p[8];
  #pragma unroll
  for (int j = 0; j < 8; ++j) p[j] = fmaxf(h[j]*inv, 0.f);
  float sq = 0.f;
  #pragma unroll
  for (int j = 0; j < 8; ++j) sq = fmaf(p[j], p[j], sq);
  #pragma unroll
  for (int mm = 1; mm < 16; mm <<= 1) sq += __shfl_xor(sq, mm, 64);
  float idn = 1.0f / (1.0f - sq);
  float o[8];
  #pragma unroll
  for (int j = 0; j < 8; ++j) o[j] = 2.0f*p[j]*idn;
  if (l16 == 0) o[0] = (1.0f + sq)*idn;
  if (gbase == 0){
    float4 lo = make_float4(o[0], o[1], o[2], o[3]);
    float4 hi = make_float4(o[4], o[5], o[6], o[7]);
    *(float4*)&XN[(size_t)node*128 + l16*8]     = lo;
    *(float4*)&XN[(size_t)node*128 + l16*8 + 4] = hi;
  }
  if (Sout && lane == 0){
    float o0n  = (1.0f + sq)*idn;
    float ynrm = fmaxf(2.0f*idn*sqrtf(sq), MINNF);
    Sout[node] = arcoshf_(fmaxf(o0n, 1.0f + EPSF)) / ynrm;
  }
}

// ---------------- bf16 MFMA GEMM (+ optional fused expmap0 epilogue -> bf16 out) ----------------
// C[n][j] = sum_c sum_k Ac[n][k]*W[j][c*128+k] (+bias)
// BM=64, BN=128, BK=64; 4 waves (2x2); reg-staged f32->bf16 with XOR-swizzled LDS.
// If S != nullptr (nchunk==1): A row = S[n] * (row with elem0 zeroed)  [logmap0 fold]
// DO_EXP: apply expmap0 row-wise via LDS, write bf16 to Cb. Else write f32 (+bias) to Cf.
template<int DO_EXP>
__global__ __launch_bounds__(256) void gemm_mfma(const float* __restrict__ A0,
                                                 const float* __restrict__ A1,
                                                 const float* __restrict__ A2,
                                                 const float* __restrict__ W,
                                                 const float* __restrict__ bias,
                                                 const float* __restrict__ S,
                                                 float* __restrict__ Cf,
                                                 unsigned short* __restrict__ Cb,
                                                 int N, int nchunk){
  __shared__ __align__(16) char smraw[64*130*4];            // 33.3 KB (union)
  short* Asm = (short*)smraw;                               // 64x64 bf16 swizzled
  short* Wsm = Asm + 64*64;                                 // 128x64 bf16 swizzled
  float* Csm = (float*)smraw;                               // 64x130 f32 (epilogue)
  int tid  = threadIdx.x;
  int lane = tid & 63;
  int wid  = tid >> 6;
  int wr   = wid >> 1;
  int wc   = wid & 1;
  int base = blockIdx.x * 64;
  int ldw  = nchunk * 128;
  int nkt  = nchunk * 2;

  const f32x4 z4 = {0.f, 0.f, 0.f, 0.f};
  f32x4 acc[2][4];
  #pragma unroll
  for (int mi = 0; mi < 2; ++mi)
    #pragma unroll
    for (int ni = 0; ni < 4; ++ni) acc[mi][ni] = z4;

  for (int kt = 0; kt < nkt; ++kt){
    int ch = kt >> 1;
    const float* Ac = (ch == 0) ? A0 : ((ch == 1) ? A1 : A2);
    int cko = (kt & 1) * 64;
    #pragma unroll
    for (int t = 0; t < 2; ++t){
      int g = tid + t*256;
      int r = g >> 3;
      int kc = (g & 7) * 8;
      int nd = base + r;
      short8v h = {0,0,0,0,0,0,0,0};
      if (nd < N){
        const float* ap = &Ac[(size_t)nd*128 + cko + kc];
        float4 v0 = *(const float4*)ap;
        float4 v1 = *(const float4*)(ap + 4);
        if (S){
          float sn = S[nd];
          if (cko == 0 && kc == 0) v0.x = 0.0f;
          v0.x*=sn; v0.y*=sn; v0.z*=sn; v0.w*=sn;
          v1.x*=sn; v1.y*=sn; v1.z*=sn; v1.w*=sn;
        }
        h = cvt8(v0, v1);
      }
      int byte = (r*128 + kc*2) ^ ((r & 7) << 4);
      *(short8v*)((char*)Asm + byte) = h;
    }
    #pragma unroll
    for (int t = 0; t < 4; ++t){
      int g = tid + t*256;
      int j = g >> 3;
      int kc = (g & 7) * 8;
      const float* wp = &W[(size_t)j*ldw + kt*64 + kc];
      float4 v0 = *(const float4*)wp;
      float4 v1 = *(const float4*)(wp + 4);
      short8v h = cvt8(v0, v1);
      int byte = (j*128 + kc*2) ^ ((j & 7) << 4);
      *(short8v*)((char*)Wsm + byte) = h;
    }
    __syncthreads();
    #pragma unroll
    for (int ks = 0; ks < 2; ++ks){
      int kb = ks*64 + (lane >> 4) * 16;
      short8v af[2], bfv[4];
      #pragma unroll
      for (int mi = 0; mi < 2; ++mi){
        int r = wr*32 + mi*16 + (lane & 15);
        af[mi] = *(const short8v*)((const char*)Asm + ((r*128 + kb) ^ ((r & 7) << 4)));
      }
      #pragma unroll
      for (int ni = 0; ni < 4; ++ni){
        int j = wc*64 + ni*16 + (lane & 15);
        bfv[ni] = *(const short8v*)((const char*)Wsm + ((j*128 + kb) ^ ((j & 7) << 4)));
      }
      #pragma unroll
      for (int mi = 0; mi < 2; ++mi)
        #pragma unroll
        for (int ni = 0; ni < 4; ++ni)
          acc[mi][ni] = __builtin_amdgcn_mfma_f32_16x16x32_bf16(af[mi], bfv[ni], acc[mi][ni], 0, 0, 0);
    }
    __syncthreads();
  }

  if (DO_EXP){
    #pragma unroll
    for (int mi = 0; mi < 2; ++mi)
      #pragma unroll
      for (int rg = 0; rg < 4; ++rg){
        int r = wr*32 + mi*16 + (lane >> 4)*4 + rg;
        #pragma unroll
        for (int ni = 0; ni < 4; ++ni){
          int col = wc*64 + ni*16 + (lane & 15);
          Csm[r*130 + col] = acc[mi][ni][rg];
        }
      }
    __syncthreads();
    for (int rr = 0; rr < 16; ++rr){
      int r = wid*16 + rr;
      int nd = base + r;
      if (nd >= N) continue;
      float2 zv = *(const float2*)&Csm[r*130 + lane*2];
      float zx = (lane == 0) ? 0.0f : zv.x;
      float xn2 = wredsum(zx*zx + zv.y*zv.y);
      float xn  = fmaxf(sqrtf(xn2), MINNF);
      float sh, chh; sinhcosh_(xn, sh, chh);
      float s = sh / xn;
      float ox = s * zx;
      float oy = s * zv.y;
      float s2 = wredsum(ox*ox + oy*oy);
      float o0 = sqrtf(fmaxf(1.0f + s2, EPSF));
      if (lane == 0) ox = o0;
      unsigned int lo = (unsigned int)(unsigned short)f2bf(ox);
      unsigned int hi = (unsigned int)(unsigned short)f2bf(oy);
      *(unsigned int*)&Cb[(size_t)nd*128 + lane*2] = (hi << 16) | lo;
    }
  } else {
    #pragma unroll
    for (int mi = 0; mi < 2; ++mi){
      #pragma unroll
      for (int rg = 0; rg < 4; ++rg){
        int row = base + wr*32 + mi*16 + (lane >> 4)*4 + rg;
        if (row < N){
          #pragma unroll
          for (int ni = 0; ni < 4; ++ni){
            int col = wc*64 + ni*16 + (lane & 15);
            float v = acc[mi][ni][rg];
            if (bias) v += bias[col];
            Cf[(size_t)row*128 + col] = v;
          }
        }
      }
    }
  }
}

extern "C" void kernel_launch(void* const* d_in, const int* in_sizes, int n_in,
                              void* d_out, int out_size, void* d_ws, size_t ws_size,
                              hipStream_t stream) {
  const float* x0 = (const float*)d_in[0];
  const int*   ei = (const int*)  d_in[1];
  const float* W0 = (const float*)d_in[2];
  const float* W1 = (const float*)d_in[3];
  const float* Wf = (const float*)d_in[4];
  const float* bf = (const float*)d_in[5];
  float* out = (float*)d_out;

  int N = in_sizes[0] / 128;
  int E = in_sizes[1] / 2;
  const int* src = ei;
  const int* dst = ei + E;

  size_t row = (size_t)N * 128;
  float* ws = (float*)d_ws;
  float* x1 = ws;                 // conv1 output (f32)
  float* x2 = ws + row;           // conv2 output (f32)
  float* Sv = ws + 2*row;         // N floats (logmap0 scale)
  size_t goff = ((2*row + (size_t)N) + 3) & ~(size_t)3;   // 16B-align
  unsigned short* g16 = (unsigned short*)(ws + goff);     // N*128 bf16 (conv gather input)
  int* rowptr   = (int*)(g16 + row);   // N+1
  int* cursor   = rowptr + (N + 1);    // N (also deg)
  int* ssrc     = cursor + N;          // E
  int* partials = ssrc + E;            // ~N/256

  dim3 blk(256);
  int nodeBlocks = (N + 3) / 4;
  int eBlocks    = (E + 255) / 256;
  int scanBlocks = (N + 255) / 256;
  int gemmBlocks = (N + 63) / 64;

  // ---- CSR build (once; shared by both layers) ----
  hipMemsetAsync(cursor, 0, (size_t)N * sizeof(int), stream);     // deg = 0
  k_hist     <<<eBlocks, blk, 0, stream>>>(dst, cursor, E);
  k_blockscan<<<scanBlocks, blk, 0, stream>>>(cursor, rowptr, partials, N);
  k_scanpart <<<1, blk, 0, stream>>>(partials, scanBlocks);
  k_addoff   <<<scanBlocks, blk, 0, stream>>>(partials, rowptr, cursor, N);
  k_scatter  <<<eBlocks, blk, 0, stream>>>(src, dst, cursor, ssrc, E);

  // ---- layer 0 ----
  k_lognorm    <<<nodeBlocks, blk, 0, stream>>>(x0, Sv, N);
  gemm_mfma<1> <<<gemmBlocks, blk, 0, stream>>>(x0, nullptr, nullptr, W0, nullptr, Sv, nullptr, g16, N, 1);
  k_conv       <<<nodeBlocks, blk, 0, stream>>>(g16, x0, rowptr, ssrc, x1, Sv, N);   // Sv = lognorm(x1)

  // ---- layer 1 ----
  gemm_mfma<1> <<<gemmBlocks, blk, 0, stream>>>(x1, nullptr, nullptr, W1, nullptr, Sv, nullptr, g16, N, 1);
  k_conv       <<<nodeBlocks, blk, 0, stream>>>(g16, x1, rowptr, ssrc, x2, nullptr, N);

  // ---- final fused GEMM ----
  gemm_mfma<0> <<<gemmBlocks, blk, 0, stream>>>(x0, x1, x2, Wf, bf, nullptr, out, nullptr, N, 3);
}